// Round 1
// baseline (389.466 us; speedup 1.0000x reference)
//
#include <hip/hip_runtime.h>
#include <math.h>

#define VOCAB 53
#define EDIM  16
#define H     32
#define G4    128   // 4*H
#define SEQ   512
#define BATCH 4096

__device__ __forceinline__ float fast_sigmoid(float x) {
    // 1/(1+exp(-x)); rcp(inf)=0 handles extremes safely
    return __builtin_amdgcn_rcpf(1.0f + __expf(-x));
}
__device__ __forceinline__ float fast_tanh(float x) {
    // tanh(x) = 2/(1+exp(-2x)) - 1 ; safe at both extremes
    float e = __expf(-2.0f * x);
    return __builtin_amdgcn_rcpf(1.0f + e) * 2.0f - 1.0f;
}

// Block: 256 threads = 4 waves; each wave handles 2 batch elements
// (lanes 0-31 -> elem A, lanes 32-63 -> elem B). Lane sub-index k (0..31)
// owns hidden unit k: gate rows k, k+32, k+64, k+96 of W_hh in registers.
__global__ __launch_bounds__(256, 2)
void lstm_seq_classifier(const int* __restrict__ x,
                         const float* __restrict__ emb,
                         const float* __restrict__ W_ih,
                         const float* __restrict__ W_hh,
                         const float* __restrict__ b_ih,
                         const float* __restrict__ b_hh,
                         const float* __restrict__ W_fc,
                         const float* __restrict__ b_fc,
                         float* __restrict__ out) {
    __shared__ float xg_lds[VOCAB * G4];   // 27136 B: per-vocab gate preactivation

    // ---- build the vocab -> gate-preactivation table (tiny) ----
    for (int idx = threadIdx.x; idx < VOCAB * G4; idx += 256) {
        int v = idx >> 7;        // /128
        int j = idx & (G4 - 1);  // %128
        float s = b_ih[j] + b_hh[j];
        const float* ev = emb + v * EDIM;
        const float* wr = W_ih + j * EDIM;
#pragma unroll
        for (int e = 0; e < EDIM; ++e) s += ev[e] * wr[e];
        xg_lds[idx] = s;
    }

    const int lane = threadIdx.x & 63;
    const int wave = threadIdx.x >> 6;
    const int half = lane >> 5;     // which batch elem within the wave
    const int k    = lane & 31;     // hidden unit owned by this lane
    const int elem = blockIdx.x * 8 + wave * 2 + half;

    // ---- load this lane's 4 gate rows of W_hh into registers (128 VGPRs) ----
    float wi[H], wf[H], wg[H], wo[H];
    const float4* W4 = reinterpret_cast<const float4*>(W_hh);
#pragma unroll
    for (int c4 = 0; c4 < H / 4; ++c4) {
        float4 a = W4[(0 * H + k) * (H / 4) + c4];
        wi[4 * c4 + 0] = a.x; wi[4 * c4 + 1] = a.y; wi[4 * c4 + 2] = a.z; wi[4 * c4 + 3] = a.w;
        float4 b = W4[(1 * H + k) * (H / 4) + c4];
        wf[4 * c4 + 0] = b.x; wf[4 * c4 + 1] = b.y; wf[4 * c4 + 2] = b.z; wf[4 * c4 + 3] = b.w;
        float4 c = W4[(2 * H + k) * (H / 4) + c4];
        wg[4 * c4 + 0] = c.x; wg[4 * c4 + 1] = c.y; wg[4 * c4 + 2] = c.z; wg[4 * c4 + 3] = c.w;
        float4 d = W4[(3 * H + k) * (H / 4) + c4];
        wo[4 * c4 + 0] = d.x; wo[4 * c4 + 1] = d.y; wo[4 * c4 + 2] = d.z; wo[4 * c4 + 3] = d.w;
    }

    __syncthreads();

    const int4* xrow4 = reinterpret_cast<const int4*>(x + elem * SEQ);

    float h = 0.0f, c = 0.0f;

    auto step = [&](int v) {
        // issue LDS reads early; consumed after the FMA block
        float xi = xg_lds[v * G4 + 0 * H + k];
        float xf = xg_lds[v * G4 + 1 * H + k];
        float xgt = xg_lds[v * G4 + 2 * H + k];
        float xo = xg_lds[v * G4 + 3 * H + k];
        float ai0 = 0.f, ai1 = 0.f, af0 = 0.f, af1 = 0.f;
        float ag0 = 0.f, ag1 = 0.f, ao0 = 0.f, ao1 = 0.f;
#pragma unroll
        for (int kp = 0; kp < H; kp += 2) {
            float hb0 = __shfl(h, kp, 32);
            float hb1 = __shfl(h, kp + 1, 32);
            ai0 += hb0 * wi[kp];     ai1 += hb1 * wi[kp + 1];
            af0 += hb0 * wf[kp];     af1 += hb1 * wf[kp + 1];
            ag0 += hb0 * wg[kp];     ag1 += hb1 * wg[kp + 1];
            ao0 += hb0 * wo[kp];     ao1 += hb1 * wo[kp + 1];
        }
        float ai = ai0 + ai1 + xi;
        float af = af0 + af1 + xf;
        float ag = ag0 + ag1 + xgt;
        float ao = ao0 + ao1 + xo;
        float gi = fast_sigmoid(ai);
        float gf = fast_sigmoid(af);
        float go = fast_sigmoid(ao);
        float gt = fast_tanh(ag);
        c = gf * c + gi * gt;
        h = go * fast_tanh(c);
    };

    // 4-step groups; prefetch next group's x one group (~1000 cyc) ahead
    int4 vcur = xrow4[0];
    for (int s4 = 0; s4 < SEQ / 4; ++s4) {
        int4 vnext = xrow4[(s4 + 1) & (SEQ / 4 - 1)];
        step(vcur.x);
        step(vcur.y);
        step(vcur.z);
        step(vcur.w);
        vcur = vnext;
    }

    // ---- final FC (1 unit) + sigmoid: reduce h*W_fc over the 32 lanes ----
    float p = h * W_fc[k];
#pragma unroll
    for (int off = 16; off >= 1; off >>= 1) p += __shfl_xor(p, off, 32);
    if (k == 0) out[elem] = fast_sigmoid(p + b_fc[0]);
}

extern "C" void kernel_launch(void* const* d_in, const int* in_sizes, int n_in,
                              void* d_out, int out_size, void* d_ws, size_t ws_size,
                              hipStream_t stream) {
    const int*   x    = (const int*)d_in[0];
    const float* emb  = (const float*)d_in[1];
    const float* W_ih = (const float*)d_in[2];
    const float* W_hh = (const float*)d_in[3];
    const float* b_ih = (const float*)d_in[4];
    const float* b_hh = (const float*)d_in[5];
    const float* W_fc = (const float*)d_in[6];
    const float* b_fc = (const float*)d_in[7];
    float* out = (float*)d_out;

    dim3 grid(BATCH / 8);   // 512 blocks, 8 batch elems per block
    dim3 block(256);
    lstm_seq_classifier<<<grid, block, 0, stream>>>(x, emb, W_ih, W_hh,
                                                    b_ih, b_hh, W_fc, b_fc, out);
}

// Round 2
// 313.152 us; speedup vs baseline: 1.2437x; 1.2437x over previous
//
#include <hip/hip_runtime.h>
#include <math.h>

#define VOCAB 53
#define EDIM  16
#define H     32
#define G4    128   // 4*H
#define SEQ   512
#define BATCH 4096

typedef float f32x2 __attribute__((ext_vector_type(2)));
typedef float f32x4 __attribute__((ext_vector_type(4)));

__device__ __forceinline__ float fast_sigmoid(float x) {
    // 1/(1+exp(-x)); rcp(inf)=0 handles extremes safely
    return __builtin_amdgcn_rcpf(1.0f + __expf(-x));
}
__device__ __forceinline__ float fast_tanh(float x) {
    // tanh(x) = 2/(1+exp(-2x)) - 1 ; safe at both extremes
    float e = __expf(-2.0f * x);
    return __builtin_amdgcn_rcpf(1.0f + e) * 2.0f - 1.0f;
}

// Block: 256 threads = 4 waves; each wave handles 2 batch elements
// (lanes 0-31 -> elem A, lanes 32-63 -> elem B). Lane sub-index k (0..31)
// owns hidden unit k: gate rows k, k+32, k+64, k+96 of W_hh in registers,
// packed as float2 pairs for v_pk_fma_f32.
__global__ __launch_bounds__(256, 2)
void lstm_seq_classifier(const int* __restrict__ x,
                         const float* __restrict__ emb,
                         const float* __restrict__ W_ih,
                         const float* __restrict__ W_hh,
                         const float* __restrict__ b_ih,
                         const float* __restrict__ b_hh,
                         const float* __restrict__ W_fc,
                         const float* __restrict__ b_fc,
                         float* __restrict__ out) {
    // xg table layout: [v][k][gate] so one ds_read_b128 fetches all 4 gates
    __shared__ float xg_tbl[VOCAB * G4];          // 27136 B
    __shared__ float h_stage[4][64];              // [wave][half*32+k], 1 KiB

    // ---- build the vocab -> gate-preactivation table (tiny) ----
    for (int idx = threadIdx.x; idx < VOCAB * G4; idx += 256) {
        int v = idx >> 7;          // vocab id
        int r = idx & (G4 - 1);
        int k = r >> 2;            // hidden unit
        int g = r & 3;             // gate
        int j = g * H + k;         // row of W_ih / bias index
        float s = b_ih[j] + b_hh[j];
        const float* ev = emb + v * EDIM;
        const float* wr = W_ih + j * EDIM;
#pragma unroll
        for (int e = 0; e < EDIM; ++e) s += ev[e] * wr[e];
        xg_tbl[idx] = s;
    }

    const int lane = threadIdx.x & 63;
    const int wave = threadIdx.x >> 6;
    const int half = lane >> 5;     // which batch elem within the wave
    const int k    = lane & 31;     // hidden unit owned by this lane
    const int elem = blockIdx.x * 8 + wave * 2 + half;

    // ---- load this lane's 4 gate rows of W_hh as float2 pairs (128 VGPRs) ----
    f32x2 wp[4][16];
    const float4* W4 = reinterpret_cast<const float4*>(W_hh);
#pragma unroll
    for (int g = 0; g < 4; ++g) {
#pragma unroll
        for (int c4 = 0; c4 < 8; ++c4) {
            float4 a = W4[(g * H + k) * 8 + c4];
            wp[g][2 * c4]     = f32x2{a.x, a.y};
            wp[g][2 * c4 + 1] = f32x2{a.z, a.w};
        }
    }

    __syncthreads();

    const int4* xrow4 = reinterpret_cast<const int4*>(x + elem * SEQ);
    const f32x4* hp = reinterpret_cast<const f32x4*>(&h_stage[wave][half * 32]);
    float* hslot = &h_stage[wave][lane];

    float h = 0.0f, c = 0.0f;

    auto step = [&](int v) {
        // all 4 gate preactivations for this (v,k): one ds_read_b128
        f32x4 xg4 = *reinterpret_cast<const f32x4*>(&xg_tbl[v * G4 + k * 4]);
        // publish previous h; same-wave DS ordering makes readback safe
        *hslot = h;
        f32x4 hq0 = hp[0], hq1 = hp[1], hq2 = hp[2], hq3 = hp[3];
        f32x4 hq4 = hp[4], hq5 = hp[5], hq6 = hp[6], hq7 = hp[7];

        f32x2 a0[4], a1[4];
        a0[0] = f32x2{xg4.x, 0.f}; a1[0] = f32x2{0.f, 0.f};
        a0[1] = f32x2{xg4.y, 0.f}; a1[1] = f32x2{0.f, 0.f};
        a0[2] = f32x2{xg4.z, 0.f}; a1[2] = f32x2{0.f, 0.f};
        a0[3] = f32x2{xg4.w, 0.f}; a1[3] = f32x2{0.f, 0.f};

        f32x4 hqs[8] = {hq0, hq1, hq2, hq3, hq4, hq5, hq6, hq7};
#pragma unroll
        for (int q = 0; q < 8; ++q) {
            f32x2 hA = f32x2{hqs[q].x, hqs[q].y};
            f32x2 hB = f32x2{hqs[q].z, hqs[q].w};
#pragma unroll
            for (int g = 0; g < 4; ++g) {
                a0[g] = __builtin_elementwise_fma(hA, wp[g][2 * q], a0[g]);
                a1[g] = __builtin_elementwise_fma(hB, wp[g][2 * q + 1], a1[g]);
            }
        }
        f32x2 si = a0[0] + a1[0];
        f32x2 sf = a0[1] + a1[1];
        f32x2 sg = a0[2] + a1[2];
        f32x2 so = a0[3] + a1[3];
        float ai = si.x + si.y;
        float af = sf.x + sf.y;
        float ag = sg.x + sg.y;
        float ao = so.x + so.y;

        float gi = fast_sigmoid(ai);
        float gf = fast_sigmoid(af);
        float go = fast_sigmoid(ao);
        float gt = fast_tanh(ag);
        c = gf * c + gi * gt;
        h = go * fast_tanh(c);
    };

    // 4-step groups; prefetch next group's x one group ahead
    int4 vcur = xrow4[0];
    for (int s4 = 0; s4 < SEQ / 4; ++s4) {
        int4 vnext = xrow4[(s4 + 1) & (SEQ / 4 - 1)];
        step(vcur.x);
        step(vcur.y);
        step(vcur.z);
        step(vcur.w);
        vcur = vnext;
    }

    // ---- final FC (1 unit) + sigmoid: reduce h*W_fc over the 32 lanes ----
    float p = h * W_fc[k];
#pragma unroll
    for (int off = 16; off >= 1; off >>= 1) p += __shfl_xor(p, off, 32);
    if (k == 0) out[elem] = fast_sigmoid(p + b_fc[0]);
}

extern "C" void kernel_launch(void* const* d_in, const int* in_sizes, int n_in,
                              void* d_out, int out_size, void* d_ws, size_t ws_size,
                              hipStream_t stream) {
    const int*   x    = (const int*)d_in[0];
    const float* emb  = (const float*)d_in[1];
    const float* W_ih = (const float*)d_in[2];
    const float* W_hh = (const float*)d_in[3];
    const float* b_ih = (const float*)d_in[4];
    const float* b_hh = (const float*)d_in[5];
    const float* W_fc = (const float*)d_in[6];
    const float* b_fc = (const float*)d_in[7];
    float* out = (float*)d_out;

    dim3 grid(BATCH / 8);   // 512 blocks, 8 batch elems per block
    dim3 block(256);
    lstm_seq_classifier<<<grid, block, 0, stream>>>(x, emb, W_ih, W_hh,
                                                    b_ih, b_hh, W_fc, b_fc, out);
}

// Round 3
// 310.875 us; speedup vs baseline: 1.2528x; 1.0073x over previous
//
#include <hip/hip_runtime.h>
#include <math.h>

#define VOCAB 53
#define EDIM  16
#define H     32
#define G4    128   // 4*H
#define SEQ   512
#define BATCH 4096

typedef float f32x2 __attribute__((ext_vector_type(2)));
typedef float f32x4 __attribute__((ext_vector_type(4)));

__device__ __forceinline__ float sigm(float x) {
    // 1/(1+exp(-x)); rcp(inf)=0 handles extremes safely
    return __builtin_amdgcn_rcpf(1.0f + __expf(-x));
}

// One batch element per wave64. Lane L owns W_hh rows L and L+64:
//   lanes 0-31 : rows L      (gate i, unit L)  and L+64 (gate g, unit L)
//   lanes 32-63: rows L      (gate f, unit L-32) and L+64 (gate o, unit L-32)
// Per step: each half computes its two gate dot products (32 pk_fma),
// applies its nonlinearities, exchanges with the other half via shfl_xor(32),
// then both halves redundantly (bitwise identically) update c,h for unit k.
// h is republished to a per-wave 32-float LDS broadcast region.
__global__ __launch_bounds__(256, 4)
void lstm_seq_classifier(const int* __restrict__ x,
                         const float* __restrict__ emb,
                         const float* __restrict__ W_ih,
                         const float* __restrict__ W_hh,
                         const float* __restrict__ b_ih,
                         const float* __restrict__ b_hh,
                         const float* __restrict__ W_fc,
                         const float* __restrict__ b_fc,
                         float* __restrict__ out) {
    __shared__ float xg_tbl[VOCAB * G4];   // [v][row j] natural layout, 27136 B
    __shared__ float h_stage[4][32];       // per-wave h broadcast, 512 B

    // ---- build the vocab -> gate-preactivation table ----
    for (int idx = threadIdx.x; idx < VOCAB * G4; idx += 256) {
        int v = idx >> 7, j = idx & 127;
        float s = b_ih[j] + b_hh[j];
        const float* ev = emb + v * EDIM;
        const float* wr = W_ih + j * EDIM;
#pragma unroll
        for (int e = 0; e < EDIM; ++e) s += ev[e] * wr[e];
        xg_tbl[idx] = s;
    }

    const int lane = threadIdx.x & 63;
    const int wave = threadIdx.x >> 6;
    const int k    = lane & 31;      // hidden unit this lane updates
    const bool lo  = (lane < 32);
    const int elem = blockIdx.x * 4 + wave;

    // ---- this lane's two W_hh rows (64 floats -> 32 f32x2 regs) ----
    f32x2 w0[16], w1[16];
    {
        const float4* r0 = reinterpret_cast<const float4*>(W_hh + lane * H);
        const float4* r1 = reinterpret_cast<const float4*>(W_hh + (lane + 64) * H);
#pragma unroll
        for (int q = 0; q < 8; ++q) {
            float4 a = r0[q];
            w0[2 * q]     = f32x2{a.x, a.y};
            w0[2 * q + 1] = f32x2{a.z, a.w};
            float4 b = r1[q];
            w1[2 * q]     = f32x2{b.x, b.y};
            w1[2 * q + 1] = f32x2{b.z, b.w};
        }
    }
    // branch-free second nonlinearity: lanes<32 need tanh = 2*sigm(2x)-1,
    // lanes>=32 need sigm(x) = 1*sigm(1x)+0
    const float tm = lo ? 2.0f : 1.0f;
    const float ts = lo ? 2.0f : 1.0f;
    const float to = lo ? -1.0f : 0.0f;

    __syncthreads();

    float* hslot = &h_stage[wave][k];                       // lanes k,k+32 same addr, same value
    const f32x4* hp = reinterpret_cast<const f32x4*>(&h_stage[wave][0]);
    const int4* xrow4 = reinterpret_cast<const int4*>(x + elem * SEQ);

    float h = 0.0f, c = 0.0f;

    auto step = [&](int v) {
        float xg0 = xg_tbl[v * G4 + lane];        // row L preactivation
        float xg1 = xg_tbl[v * G4 + 64 + lane];   // row L+64
        *hslot = h;   // same-wave DS ordering: later reads see this write
        f32x2 a0{xg0, 0.f}, b0{0.f, 0.f};
        f32x2 a1{xg1, 0.f}, b1{0.f, 0.f};
#pragma unroll
        for (int q = 0; q < 4; ++q) {
            f32x4 hq0 = hp[2 * q];       // broadcast reads (all lanes same addr)
            f32x4 hq1 = hp[2 * q + 1];
            f32x2 hA{hq0.x, hq0.y}, hB{hq0.z, hq0.w};
            f32x2 hC{hq1.x, hq1.y}, hD{hq1.z, hq1.w};
            a0 = __builtin_elementwise_fma(hA, w0[4 * q],     a0);
            b0 = __builtin_elementwise_fma(hB, w0[4 * q + 1], b0);
            a0 = __builtin_elementwise_fma(hC, w0[4 * q + 2], a0);
            b0 = __builtin_elementwise_fma(hD, w0[4 * q + 3], b0);
            a1 = __builtin_elementwise_fma(hA, w1[4 * q],     a1);
            b1 = __builtin_elementwise_fma(hB, w1[4 * q + 1], b1);
            a1 = __builtin_elementwise_fma(hC, w1[4 * q + 2], a1);
            b1 = __builtin_elementwise_fma(hD, w1[4 * q + 3], b1);
        }
        f32x2 s0p = a0 + b0;
        f32x2 s1p = a1 + b1;
        float A0 = s0p.x + s0p.y;   // lanes<32: i pre-act ; lanes>=32: f pre-act
        float A1 = s1p.x + s1p.y;   // lanes<32: g pre-act ; lanes>=32: o pre-act
        float s0 = sigm(A0);                      // sig(i) | sig(f)
        float s1 = __builtin_fmaf(ts, sigm(tm * A1), to);  // tanh(g) | sig(o)
        float sw0 = __shfl_xor(s0, 32);           // sig(f) | sig(i)
        float sw1 = __shfl_xor(s1, 32);           // sig(o) | tanh(g)
        float F = lo ? sw0 : s0;
        float I = lo ? s0  : sw0;
        float G = lo ? s1  : sw1;
        float O = lo ? sw1 : s1;
        c = F * c + I * G;
        float t = __builtin_fmaf(2.0f, sigm(2.0f * c), -1.0f);  // tanh(c)
        h = O * t;
    };

    // 4-step groups; prefetch next group's x one group ahead
    int4 vcur = xrow4[0];
    for (int s4 = 0; s4 < SEQ / 4; ++s4) {
        int4 vnext = xrow4[(s4 + 1) & (SEQ / 4 - 1)];
        step(vcur.x);
        step(vcur.y);
        step(vcur.z);
        step(vcur.w);
        vcur = vnext;
    }

    // ---- final FC (1 unit) + sigmoid: reduce h*W_fc over the 32 units ----
    float p = h * W_fc[k];
#pragma unroll
    for (int off = 16; off >= 1; off >>= 1) p += __shfl_xor(p, off);
    if (lane == 0) out[elem] = sigm(p + b_fc[0]);
}

extern "C" void kernel_launch(void* const* d_in, const int* in_sizes, int n_in,
                              void* d_out, int out_size, void* d_ws, size_t ws_size,
                              hipStream_t stream) {
    const int*   x    = (const int*)d_in[0];
    const float* emb  = (const float*)d_in[1];
    const float* W_ih = (const float*)d_in[2];
    const float* W_hh = (const float*)d_in[3];
    const float* b_ih = (const float*)d_in[4];
    const float* b_hh = (const float*)d_in[5];
    const float* W_fc = (const float*)d_in[6];
    const float* b_fc = (const float*)d_in[7];
    float* out = (float*)d_out;

    dim3 grid(BATCH / 4);   // 1024 blocks, 1 elem per wave, 4 waves per block
    dim3 block(256);
    lstm_seq_classifier<<<grid, block, 0, stream>>>(x, emb, W_ih, W_hh,
                                                    b_ih, b_hh, W_fc, b_fc, out);
}

// Round 4
// 296.362 us; speedup vs baseline: 1.3142x; 1.0490x over previous
//
#include <hip/hip_runtime.h>
#include <math.h>

#define VOCAB 53
#define EDIM  16
#define H     32
#define G4    128   // 4*H
#define SEQ   512
#define BATCH 4096

#define LOG2E 1.4426950408889634f

typedef float f32x2 __attribute__((ext_vector_type(2)));
typedef float f32x4 __attribute__((ext_vector_type(4)));

// pinned packed FMA: acc = a*b + acc (2 lanes of f32). "v" constraints force
// arch-VGPR homing for the weights (AGPRs are not valid for "v").
#define PKFMA(acc, a, b) \
    asm("v_pk_fma_f32 %0, %1, %2, %0" : "+v"(acc) : "v"(a), "v"(b))

__device__ __forceinline__ float exp2_hw(float x) {   // 2^x, quarter-rate trans
    float r;
    asm("v_exp_f32 %0, %1" : "=v"(r) : "v"(x));
    return r;
}

// One batch element per wave64. Lane L owns W_hh rows L (i|f gates) and
// L+64 (g|o gates). All gate math is done in the exp2 domain: rows and the
// xg table are pre-scaled by -log2e (g rows by -2log2e), so sigmoid is
// rcp(1+exp2(acc)) with no extra multiplies. c is kept scaled by -2log2e.
__global__ __launch_bounds__(256, 4)
void lstm_seq_classifier(const int* __restrict__ x,
                         const float* __restrict__ emb,
                         const float* __restrict__ W_ih,
                         const float* __restrict__ W_hh,
                         const float* __restrict__ b_ih,
                         const float* __restrict__ b_hh,
                         const float* __restrict__ W_fc,
                         const float* __restrict__ b_fc,
                         float* __restrict__ out) {
    __shared__ float xg_tbl[VOCAB * G4];   // 27136 B, pre-scaled -s_j * preact
    __shared__ float h_stage[4][32];       // per-wave h broadcast

    // ---- build vocab -> (-scale * gate-preactivation) table ----
    for (int idx = threadIdx.x; idx < VOCAB * G4; idx += 256) {
        int v = idx >> 7, j = idx & 127;
        float s = b_ih[j] + b_hh[j];
        const float* ev = emb + v * EDIM;
        const float* wr = W_ih + j * EDIM;
#pragma unroll
        for (int e = 0; e < EDIM; ++e) s += ev[e] * wr[e];
        float sc = (j >= 64 && j < 96) ? (2.0f * LOG2E) : LOG2E;  // g rows doubled
        xg_tbl[idx] = -sc * s;
    }

    const int lane = threadIdx.x & 63;
    const int wave = threadIdx.x >> 6;
    const int k    = lane & 31;      // hidden unit this lane updates
    const bool lo  = (lane < 32);
    const int elem = blockIdx.x * 4 + wave;

    // ---- this lane's two W_hh rows, negated+scaled, as f32x2 pairs ----
    const float sc0 = -LOG2E;                       // rows 0-63: i|f
    const float sc1 = lo ? (-2.0f * LOG2E) : -LOG2E; // row L+64: g (lo) | o (hi)
    f32x2 w0[16], w1[16];
    {
        const float4* r0 = reinterpret_cast<const float4*>(W_hh + lane * H);
        const float4* r1 = reinterpret_cast<const float4*>(W_hh + (lane + 64) * H);
#pragma unroll
        for (int q = 0; q < 8; ++q) {
            float4 a = r0[q];
            w0[2 * q]     = f32x2{sc0 * a.x, sc0 * a.y};
            w0[2 * q + 1] = f32x2{sc0 * a.z, sc0 * a.w};
            float4 b = r1[q];
            w1[2 * q]     = f32x2{sc1 * b.x, sc1 * b.y};
            w1[2 * q + 1] = f32x2{sc1 * b.z, sc1 * b.w};
        }
    }
    // second nonlinearity constants: lanes<32 produce Gt = -2log2e*tanh(g)
    // = fma(-4log2e, u, 2log2e); lanes>=32 produce O = u (ts=1, to=0)
    const float ts = lo ? (-4.0f * LOG2E) : 1.0f;
    const float to = lo ? (2.0f * LOG2E) : 0.0f;

    __syncthreads();

    float* hslot = &h_stage[wave][k];   // lanes k and k+32: same addr, same value
    const f32x4* hp = reinterpret_cast<const f32x4*>(&h_stage[wave][0]);
    const int4* xrow4 = reinterpret_cast<const int4*>(x + elem * SEQ);

    float h = 0.0f, c = 0.0f;   // c lives scaled by -2log2e

    auto step = [&](int v) {
        float xg0 = xg_tbl[v * G4 + lane];        // -s * (row L preact)
        float xg1 = xg_tbl[v * G4 + 64 + lane];   // -s * (row L+64 preact)
        *hslot = h;   // same-wave DS ordering: following reads see this
        f32x4 hq0 = hp[0], hq1 = hp[1], hq2 = hp[2], hq3 = hp[3];
        f32x4 hq4 = hp[4], hq5 = hp[5], hq6 = hp[6], hq7 = hp[7];

        f32x2 a0{xg0, 0.f}, b0{0.f, 0.f};
        f32x2 a1{xg1, 0.f}, b1{0.f, 0.f};
        // aligned pair extracts (subregister, no movs)
        f32x2 hA, hB;
#define QUAD(hq, i0, i1)                                   \
        hA = f32x2{hq.x, hq.y}; hB = f32x2{hq.z, hq.w};    \
        PKFMA(a0, hA, w0[i0]); PKFMA(b0, hB, w0[i1]);      \
        PKFMA(a1, hA, w1[i0]); PKFMA(b1, hB, w1[i1]);
        QUAD(hq0, 0, 1)  QUAD(hq1, 2, 3)  QUAD(hq2, 4, 5)  QUAD(hq3, 6, 7)
        QUAD(hq4, 8, 9)  QUAD(hq5, 10, 11) QUAD(hq6, 12, 13) QUAD(hq7, 14, 15)
#undef QUAD
        f32x2 s0p = a0 + b0;          // v_pk_add_f32
        f32x2 s1p = a1 + b1;
        float A0 = s0p.x + s0p.y;     // = -log2e * (i|f preact)
        float A1 = s1p.x + s1p.y;     // = -2log2e*g | -log2e*o

        float u0 = __builtin_amdgcn_rcpf(1.0f + exp2_hw(A0));  // sig(i)|sig(f)
        float u1 = __builtin_amdgcn_rcpf(1.0f + exp2_hw(A1));  // sig(2g)|sig(o)
        float s1 = __builtin_fmaf(ts, u1, to);   // Gt(scaled) | O

        float sw0 = __shfl_xor(u0, 32);          // sig(f) | sig(i)
        float sw1 = __shfl_xor(s1, 32);          // O      | Gt
        float F  = lo ? sw0 : u0;
        float I  = lo ? u0  : sw0;
        float Gt = lo ? s1  : sw1;
        float O  = lo ? sw1 : s1;
        c = __builtin_fmaf(F, c, I * Gt);                       // scaled c
        float t = __builtin_fmaf(2.0f,
                      __builtin_amdgcn_rcpf(1.0f + exp2_hw(c)), -1.0f); // tanh
        h = O * t;
    };

    // 4-step groups; prefetch next group's x one group ahead
    int4 vcur = xrow4[0];
    for (int s4 = 0; s4 < SEQ / 4; ++s4) {
        int4 vnext = xrow4[(s4 + 1) & (SEQ / 4 - 1)];
        step(vcur.x);
        step(vcur.y);
        step(vcur.z);
        step(vcur.w);
        vcur = vnext;
    }

    // ---- final FC (1 unit) + sigmoid over the 32 units (per 32-lane half) ----
    float p = h * W_fc[k];
#pragma unroll
    for (int off = 16; off >= 1; off >>= 1) p += __shfl_xor(p, off);
    if (lane == 0) {
        float m = -LOG2E * (p + b_fc[0]);
        out[elem] = __builtin_amdgcn_rcpf(1.0f + exp2_hw(m));
    }
}

extern "C" void kernel_launch(void* const* d_in, const int* in_sizes, int n_in,
                              void* d_out, int out_size, void* d_ws, size_t ws_size,
                              hipStream_t stream) {
    const int*   x    = (const int*)d_in[0];
    const float* emb  = (const float*)d_in[1];
    const float* W_ih = (const float*)d_in[2];
    const float* W_hh = (const float*)d_in[3];
    const float* b_ih = (const float*)d_in[4];
    const float* b_hh = (const float*)d_in[5];
    const float* W_fc = (const float*)d_in[6];
    const float* b_fc = (const float*)d_in[7];
    float* out = (float*)d_out;

    dim3 grid(BATCH / 4);   // 1024 blocks, 1 elem per wave, 4 waves per block
    dim3 block(256);
    lstm_seq_classifier<<<grid, block, 0, stream>>>(x, emb, W_ih, W_hh,
                                                    b_ih, b_hh, W_fc, b_fc, out);
}

// Round 5
// 284.470 us; speedup vs baseline: 1.3691x; 1.0418x over previous
//
#include <hip/hip_runtime.h>
#include <math.h>

#define VOCAB 53
#define EDIM  16
#define H     32
#define G4    128   // 4*H
#define SEQ   512
#define BATCH 4096

#define LOG2E 1.4426950408889634f

typedef _Float16 f16x2 __attribute__((ext_vector_type(2)));
typedef _Float16 f16x8 __attribute__((ext_vector_type(8)));
typedef float f32x4 __attribute__((ext_vector_type(4)));

__device__ __forceinline__ float dot2(f16x2 a, f16x2 b, float c) {
#if __has_builtin(__builtin_amdgcn_fdot2)
    return __builtin_amdgcn_fdot2(a, b, c, false);
#else
    float r = c;
    asm("v_dot2_f32_f16 %0, %1, %2, %0" : "+v"(r) : "v"(a), "v"(b));
    return r;
#endif
}

__device__ __forceinline__ float exp2_hw(float x) {   // 2^x
    float r;
    asm("v_exp_f32 %0, %1" : "=v"(r) : "v"(x));
    return r;
}

// One batch element per wave64. Lane L owns W_hh rows L (i|f) and L+64 (g|o),
// stored as packed f16x2 (32 VGPRs total) consumed by v_dot2_f32_f16 with f32
// accumulation. All gate math in the exp2 domain (scales folded into the f16
// weights and the f32 xg table); c kept scaled by -2log2e.
__global__ __launch_bounds__(256, 4)
void lstm_seq_classifier(const int* __restrict__ x,
                         const float* __restrict__ emb,
                         const float* __restrict__ W_ih,
                         const float* __restrict__ W_hh,
                         const float* __restrict__ b_ih,
                         const float* __restrict__ b_hh,
                         const float* __restrict__ W_fc,
                         const float* __restrict__ b_fc,
                         float* __restrict__ out) {
    __shared__ float xg_tbl[VOCAB * G4];              // 27136 B, -scale*preact
    __shared__ __align__(16) _Float16 h_half[4][32];  // per-wave h broadcast (f16)
    __shared__ int x_lds[4][SEQ];                     // per-wave token ids, 8 KiB

    const int lane = threadIdx.x & 63;
    const int wave = threadIdx.x >> 6;
    const int k    = lane & 31;
    const bool lo  = (lane < 32);
    const int elem = blockIdx.x * 4 + wave;

    // ---- stage this wave's token sequence into LDS (coalesced) ----
    for (int i = lane; i < SEQ; i += 64) x_lds[wave][i] = x[elem * SEQ + i];

    // ---- build vocab -> (-scale * gate-preactivation) table ----
    for (int idx = threadIdx.x; idx < VOCAB * G4; idx += 256) {
        int v = idx >> 7, j = idx & 127;
        float s = b_ih[j] + b_hh[j];
        const float* ev = emb + v * EDIM;
        const float* wr = W_ih + j * EDIM;
#pragma unroll
        for (int e = 0; e < EDIM; ++e) s += ev[e] * wr[e];
        float sc = (j >= 64 && j < 96) ? (2.0f * LOG2E) : LOG2E;  // g rows doubled
        xg_tbl[idx] = -sc * s;
    }

    // ---- this lane's two W_hh rows as scaled f16 pairs (32 VGPRs) ----
    const float sc0 = -LOG2E;                         // rows 0-63: i|f
    const float sc1 = lo ? (-2.0f * LOG2E) : -LOG2E;  // row L+64: g (lo) | o (hi)
    f16x2 w0[16], w1[16];
    {
        const f32x4* r0 = reinterpret_cast<const f32x4*>(W_hh + lane * H);
        const f32x4* r1 = reinterpret_cast<const f32x4*>(W_hh + (lane + 64) * H);
#pragma unroll
        for (int q = 0; q < 8; ++q) {
            f32x4 a = r0[q];
            w0[2 * q]     = f16x2{(_Float16)(sc0 * a.x), (_Float16)(sc0 * a.y)};
            w0[2 * q + 1] = f16x2{(_Float16)(sc0 * a.z), (_Float16)(sc0 * a.w)};
            f32x4 b = r1[q];
            w1[2 * q]     = f16x2{(_Float16)(sc1 * b.x), (_Float16)(sc1 * b.y)};
            w1[2 * q + 1] = f16x2{(_Float16)(sc1 * b.z), (_Float16)(sc1 * b.w)};
        }
    }
    // lanes<32: Gt = fma(-4log2e, sig, 2log2e) ; lanes>=32: O = sig
    const float ts = lo ? (-4.0f * LOG2E) : 1.0f;
    const float to = lo ? (2.0f * LOG2E) : 0.0f;

    __syncthreads();

    _Float16* hslot = &h_half[wave][k];   // lanes k,k+32: same addr, same value
    const f16x8* hp = reinterpret_cast<const f16x8*>(&h_half[wave][0]);

    float h = 0.0f, c = 0.0f;   // c scaled by -2log2e

    int v = x_lds[wave][0];
    for (int s = 0; s < SEQ; ++s) {
        int vn = x_lds[wave][(s + 1) & (SEQ - 1)];   // uniform broadcast prefetch
        float xg0 = xg_tbl[v * G4 + lane];
        float xg1 = xg_tbl[v * G4 + 64 + lane];
        *hslot = (_Float16)h;   // same-wave DS ordering: reads below see this
        f16x8 q0 = hp[0], q1 = hp[1], q2 = hp[2], q3 = hp[3];

        float a0 = xg0, b0 = 0.0f, a1 = xg1, b1 = 0.0f;
#define PAIR(q, j) __builtin_shufflevector(q, q, 2 * (j), 2 * (j) + 1)
        f16x2 p;
        p = PAIR(q0, 0); a0 = dot2(p, w0[0],  a0); a1 = dot2(p, w1[0],  a1);
        p = PAIR(q0, 1); a0 = dot2(p, w0[1],  a0); a1 = dot2(p, w1[1],  a1);
        p = PAIR(q0, 2); a0 = dot2(p, w0[2],  a0); a1 = dot2(p, w1[2],  a1);
        p = PAIR(q0, 3); a0 = dot2(p, w0[3],  a0); a1 = dot2(p, w1[3],  a1);
        p = PAIR(q1, 0); a0 = dot2(p, w0[4],  a0); a1 = dot2(p, w1[4],  a1);
        p = PAIR(q1, 1); a0 = dot2(p, w0[5],  a0); a1 = dot2(p, w1[5],  a1);
        p = PAIR(q1, 2); a0 = dot2(p, w0[6],  a0); a1 = dot2(p, w1[6],  a1);
        p = PAIR(q1, 3); a0 = dot2(p, w0[7],  a0); a1 = dot2(p, w1[7],  a1);
        p = PAIR(q2, 0); b0 = dot2(p, w0[8],  b0); b1 = dot2(p, w1[8],  b1);
        p = PAIR(q2, 1); b0 = dot2(p, w0[9],  b0); b1 = dot2(p, w1[9],  b1);
        p = PAIR(q2, 2); b0 = dot2(p, w0[10], b0); b1 = dot2(p, w1[10], b1);
        p = PAIR(q2, 3); b0 = dot2(p, w0[11], b0); b1 = dot2(p, w1[11], b1);
        p = PAIR(q3, 0); b0 = dot2(p, w0[12], b0); b1 = dot2(p, w1[12], b1);
        p = PAIR(q3, 1); b0 = dot2(p, w0[13], b0); b1 = dot2(p, w1[13], b1);
        p = PAIR(q3, 2); b0 = dot2(p, w0[14], b0); b1 = dot2(p, w1[14], b1);
        p = PAIR(q3, 3); b0 = dot2(p, w0[15], b0); b1 = dot2(p, w1[15], b1);
#undef PAIR
        float A0 = a0 + b0;    // -log2e * (i|f preact)
        float A1 = a1 + b1;    // -2log2e*g | -log2e*o

        float u0 = __builtin_amdgcn_rcpf(1.0f + exp2_hw(A0));  // sig(i)|sig(f)
        float u1 = __builtin_amdgcn_rcpf(1.0f + exp2_hw(A1));  // sig(2g)|sig(o)
        float s1 = __builtin_fmaf(ts, u1, to);   // Gt(scaled) | O

        float sw0 = __shfl_xor(u0, 32);          // sig(f) | sig(i)
        float sw1 = __shfl_xor(s1, 32);          // O      | Gt
        float F  = lo ? sw0 : u0;
        float I  = lo ? u0  : sw0;
        float Gt = lo ? s1  : sw1;
        float O  = lo ? sw1 : s1;
        c = __builtin_fmaf(F, c, I * Gt);                       // scaled c
        float t = __builtin_fmaf(2.0f,
                      __builtin_amdgcn_rcpf(1.0f + exp2_hw(c)), -1.0f); // tanh
        h = O * t;
        v = vn;
    }

    // ---- final FC (1 unit) + sigmoid over the 32 units (per 32-lane half) ----
    float p = h * W_fc[k];
#pragma unroll
    for (int off = 16; off >= 1; off >>= 1) p += __shfl_xor(p, off);
    if (lane == 0) {
        float m = -LOG2E * (p + b_fc[0]);
        out[elem] = __builtin_amdgcn_rcpf(1.0f + exp2_hw(m));
    }
}

extern "C" void kernel_launch(void* const* d_in, const int* in_sizes, int n_in,
                              void* d_out, int out_size, void* d_ws, size_t ws_size,
                              hipStream_t stream) {
    const int*   x    = (const int*)d_in[0];
    const float* emb  = (const float*)d_in[1];
    const float* W_ih = (const float*)d_in[2];
    const float* W_hh = (const float*)d_in[3];
    const float* b_ih = (const float*)d_in[4];
    const float* b_hh = (const float*)d_in[5];
    const float* W_fc = (const float*)d_in[6];
    const float* b_fc = (const float*)d_in[7];
    float* out = (float*)d_out;

    dim3 grid(BATCH / 4);   // 1024 blocks, 1 elem per wave, 4 waves per block
    dim3 block(256);
    lstm_seq_classifier<<<grid, block, 0, stream>>>(x, emb, W_ih, W_hh,
                                                    b_ih, b_hh, W_fc, b_fc, out);
}

// Round 6
// 261.686 us; speedup vs baseline: 1.4883x; 1.0871x over previous
//
#include <hip/hip_runtime.h>

#define VOCAB 53
#define EDIM  16
#define H     32
#define G4    128   // 4*H
#define SEQ   512
#define BATCH 4096

#define LOG2E 1.4426950408889634f

typedef _Float16 f16x2 __attribute__((ext_vector_type(2)));
typedef _Float16 f16x4 __attribute__((ext_vector_type(4)));
typedef float f32x2 __attribute__((ext_vector_type(2)));
typedef float f32x4 __attribute__((ext_vector_type(4)));

__device__ __forceinline__ float dot2(f16x2 a, f16x2 b, float c) {
    return __builtin_amdgcn_fdot2(a, b, c, false);
}

__device__ __forceinline__ float exp2_hw(float x) {   // 2^x
    float r;
    asm("v_exp_f32 %0, %1" : "=v"(r) : "v"(x));
    return r;
}

// v_permlane32_swap_b32 a, b : a.lanes[0:31] <-> b.lanes[32:63].
// With a=b=x on entry: a becomes x's hi-half value broadcast to all 64 lanes,
// b becomes x's lo-half value broadcast to all 64 lanes.
__device__ __forceinline__ void bcast_halves(float& hi_all, float& lo_all) {
    asm("v_permlane32_swap_b32 %0, %1" : "+v"(hi_all), "+v"(lo_all));
}

// One batch element per wave64. Lane L owns W_hh rows L (i|f) and L+64 (g|o)
// as packed f16x2 (32 VGPRs), consumed by v_dot2_f32_f16 with f32 accumulate.
// All gate math in the exp2 domain (scales folded into the f16 weights and the
// f32 xg table); c kept scaled by -2log2e. x reads are scalar (s_load).
__global__ __launch_bounds__(256)
__attribute__((amdgpu_waves_per_eu(4, 4)))
void lstm_seq_classifier(const int* __restrict__ x,
                         const float* __restrict__ emb,
                         const float* __restrict__ W_ih,
                         const float* __restrict__ W_hh,
                         const float* __restrict__ b_ih,
                         const float* __restrict__ b_hh,
                         const float* __restrict__ W_fc,
                         const float* __restrict__ b_fc,
                         float* __restrict__ out) {
    // xg2[v][L] = ( -log2e * preact(row L), scB * preact(row L+64) )
    // scB = -2log2e for L<32 (g gate), -log2e for L>=32 (o gate)
    __shared__ f32x2 xg2[VOCAB * 64];                 // 27136 B
    __shared__ __align__(16) _Float16 h_half[4][32];  // per-wave h broadcast

    const int lane = threadIdx.x & 63;
    const int wave = threadIdx.x >> 6;
    const int k    = lane & 31;
    const bool lo  = (lane < 32);
    const int elem = blockIdx.x * 4 + wave;

    // ---- build vocab -> scaled gate-preactivation pair table ----
    for (int idx = threadIdx.x; idx < VOCAB * 64; idx += 256) {
        int v = idx >> 6, L = idx & 63;
        float s0 = b_ih[L] + b_hh[L];
        float s1 = b_ih[L + 64] + b_hh[L + 64];
        const float* ev = emb + v * EDIM;
        const float* wr0 = W_ih + L * EDIM;
        const float* wr1 = W_ih + (L + 64) * EDIM;
#pragma unroll
        for (int e = 0; e < EDIM; ++e) {
            float ee = ev[e];
            s0 += ee * wr0[e];
            s1 += ee * wr1[e];
        }
        float scB = (L < 32) ? (-2.0f * LOG2E) : -LOG2E;
        xg2[idx] = f32x2{-LOG2E * s0, scB * s1};
    }

    // ---- this lane's two W_hh rows as scaled f16 pairs (32 VGPRs) ----
    const float sc0 = -LOG2E;                         // rows 0-63: i|f
    const float sc1 = lo ? (-2.0f * LOG2E) : -LOG2E;  // row L+64: g (lo) | o (hi)
    f16x2 w0[16], w1[16];
    {
        const f32x4* r0 = reinterpret_cast<const f32x4*>(W_hh + lane * H);
        const f32x4* r1 = reinterpret_cast<const f32x4*>(W_hh + (lane + 64) * H);
#pragma unroll
        for (int q = 0; q < 8; ++q) {
            f32x4 a = r0[q];
            w0[2 * q]     = f16x2{(_Float16)(sc0 * a.x), (_Float16)(sc0 * a.y)};
            w0[2 * q + 1] = f16x2{(_Float16)(sc0 * a.z), (_Float16)(sc0 * a.w)};
            f32x4 b = r1[q];
            w1[2 * q]     = f16x2{(_Float16)(sc1 * b.x), (_Float16)(sc1 * b.y)};
            w1[2 * q + 1] = f16x2{(_Float16)(sc1 * b.z), (_Float16)(sc1 * b.w)};
        }
    }
    // lanes<32: Gt = fma(-4log2e, sig, 2log2e) ; lanes>=32: O = sig
    const float ts = lo ? (-4.0f * LOG2E) : 1.0f;
    const float to = lo ? (2.0f * LOG2E) : 0.0f;

    __syncthreads();

    _Float16* hslot = &h_half[wave][k];   // lanes k,k+32: same addr, same value
    const f16x4* h4 = reinterpret_cast<const f16x4*>(&h_half[wave][0]);
    const f32x2* xgrow_base = xg2 + lane;  // + v*64 per step

    // uniform (scalar) x addressing
    const int sbase = __builtin_amdgcn_readfirstlane(elem) * SEQ;

    float h = 0.0f, c = 0.0f;   // c scaled by -2log2e
    *hslot = (_Float16)0.0f;    // step-0 h broadcast

    int vcur = x[sbase];
    for (int s = 0; s < SEQ; ++s) {
        int vnext = x[sbase + ((s + 1) & (SEQ - 1))];   // scalar prefetch
        f32x2 xg = xgrow_base[vcur * 64];               // one ds_read_b64
        *hslot = (_Float16)h;   // same-wave DS ordering: reads below see this

        float a0 = xg.x, b0 = 0.0f, a1 = xg.y, b1 = 0.0f;
#pragma unroll
        for (int j = 0; j < 8; ++j) {                   // 8 x ds_read_b64
            f16x4 hq = h4[j];
            f16x2 pA = __builtin_shufflevector(hq, hq, 0, 1);  // low reg (free)
            f16x2 pB = __builtin_shufflevector(hq, hq, 2, 3);  // high reg (free)
            a0 = dot2(pA, w0[2 * j],     a0);
            a1 = dot2(pA, w1[2 * j],     a1);
            b0 = dot2(pB, w0[2 * j + 1], b0);
            b1 = dot2(pB, w1[2 * j + 1], b1);
        }
        float A0 = a0 + b0;    // -log2e * (i|f preact)
        float A1 = a1 + b1;    // -2log2e*g | -log2e*o

        float u0 = __builtin_amdgcn_rcpf(1.0f + exp2_hw(A0));  // sig(i)|sig(f)
        float u1 = __builtin_amdgcn_rcpf(1.0f + exp2_hw(A1));  // sig(2g)|sig(o)
        float s1 = __builtin_fmaf(ts, u1, to);   // Gt(scaled) | O

        float F = u0, I = u0;   // after swap: F=sig(f) all lanes, I=sig(i) all
        bcast_halves(F, I);
        float O = s1, G = s1;   // after swap: O=O all lanes, G=Gt all lanes
        bcast_halves(O, G);

        c = __builtin_fmaf(F, c, I * G);                        // scaled c
        float t = __builtin_fmaf(2.0f,
                      __builtin_amdgcn_rcpf(1.0f + exp2_hw(c)), -1.0f); // tanh
        h = O * t;
        vcur = vnext;
    }

    // ---- final FC (1 unit) + sigmoid over the 32 units (per 32-lane half) ----
    float p = h * W_fc[k];
#pragma unroll
    for (int off = 16; off >= 1; off >>= 1) p += __shfl_xor(p, off);
    if (lane == 0) {
        float m = -LOG2E * (p + b_fc[0]);
        out[elem] = __builtin_amdgcn_rcpf(1.0f + exp2_hw(m));
    }
}

extern "C" void kernel_launch(void* const* d_in, const int* in_sizes, int n_in,
                              void* d_out, int out_size, void* d_ws, size_t ws_size,
                              hipStream_t stream) {
    const int*   x    = (const int*)d_in[0];
    const float* emb  = (const float*)d_in[1];
    const float* W_ih = (const float*)d_in[2];
    const float* W_hh = (const float*)d_in[3];
    const float* b_ih = (const float*)d_in[4];
    const float* b_hh = (const float*)d_in[5];
    const float* W_fc = (const float*)d_in[6];
    const float* b_fc = (const float*)d_in[7];
    float* out = (float*)d_out;

    dim3 grid(BATCH / 4);   // 1024 blocks, 1 elem per wave, 4 waves per block
    dim3 block(256);
    lstm_seq_classifier<<<grid, block, 0, stream>>>(x, emb, W_ih, W_hh,
                                                    b_ih, b_hh, W_fc, b_fc, out);
}

// Round 8
// 180.835 us; speedup vs baseline: 2.1537x; 1.4471x over previous
//
#include <hip/hip_runtime.h>

#define VOCAB 53
#define EDIM  16
#define H     32
#define SEQ   512
#define BATCH 4096
#define LOG2E 1.4426950408889634f
#define XRS   132   // xg row stride in f32 words (%4==0 for b128 alignment)
#define RSC   2048.0f      // residual scale (2^11) keeps lo parts in f16 normal range
#define RSCI  (1.0f/2048.0f)

typedef _Float16 f16x8 __attribute__((ext_vector_type(8)));
typedef float f32x4 __attribute__((ext_vector_type(4)));

__device__ __forceinline__ float exp2_hw(float x) {
    float r; asm("v_exp_f32 %0, %1" : "=v"(r) : "v"(x)); return r;
}
// rcp(1 + 2^xs): sigmoid when xs = -log2e * z (scales pre-folded into weights/tables)
__device__ __forceinline__ float sig_exp2(float xs) {
    return __builtin_amdgcn_rcpf(1.0f + exp2_hw(xs));
}

// permuted row rp = 16*m + 4*s + g  <->  original W row g*32 + (4m+s)
// (so mfma chunk m gives lane (q,c) the 4 gates i,f,g,o of unit 4m+q in D[0..3])
__device__ __forceinline__ void decode_row(int rp, int& orig, float& scale) {
    int m = rp >> 4, rem = rp & 15, s = rem >> 2, g = rem & 3;
    orig = g * 32 + 4 * m + s;
    scale = (g == 2) ? (-2.0f * LOG2E) : (-LOG2E);   // g-gate doubled: tanh(g)=2*sig(2g)-1
}

// 256 blocks x 512 threads. Each block owns 16 batch elements; its 8 waves
// split the 128 gate-rows (one 16x16x32 f16 MFMA row-chunk each; W rows
// permuted so each lane gets i,f,g,o of one hidden unit). h exchanged via a
// double-buffered LDS tile, one barrier per step. Weights AND h are carried as
// f16 hi + scaled-f16 residual (no subnormals); 3 MFMAs reconstruct near-f32
// precision: D = Ahi*Bhi + (Alo_s*Bhi + Ahi*Blo_s)/2048 + xg.
__global__ __launch_bounds__(512, 1)
void lstm_seq_classifier(const int* __restrict__ x,
                         const float* __restrict__ emb,
                         const float* __restrict__ W_ih,
                         const float* __restrict__ W_hh,
                         const float* __restrict__ b_ih,
                         const float* __restrict__ b_hh,
                         const float* __restrict__ W_fc,
                         const float* __restrict__ b_fc,
                         float* __restrict__ out) {
    __shared__ float xg_perm[VOCAB * XRS];                  // 27,984 B (f32, exact)
    __shared__ _Float16 whi[128 * 32];                      // 8,192 B
    __shared__ _Float16 wlo[128 * 32];                      // 8,192 B (x2048 residual)
    __shared__ __align__(16) _Float16 hhi_buf[2 * 16 * 32]; // 2,048 B
    __shared__ __align__(16) _Float16 hlo_buf[2 * 16 * 32]; // 2,048 B (x2048 residual)
    __shared__ float red[16 * 32];                          // 2,048 B

    const int tid  = threadIdx.x;
    const int lane = tid & 63;
    const int w    = tid >> 6;      // wave index = mfma row-chunk m
    const int col  = lane & 15;     // batch column (B/C/D col) & A row-in-chunk
    const int q    = lane >> 4;

    // ---- vocab -> permuted, scaled gate-preactivation table (f32 exact) ----
    for (int idx = tid; idx < VOCAB * 128; idx += 512) {
        int v = idx >> 7, rp = idx & 127;
        int orig; float scale; decode_row(rp, orig, scale);
        float acc = b_ih[orig] + b_hh[orig];
        const float* ev = emb + v * EDIM;
        const float* wr = W_ih + orig * EDIM;
#pragma unroll
        for (int e = 0; e < EDIM; ++e) acc += ev[e] * wr[e];
        xg_perm[v * XRS + rp] = scale * acc;
    }
    // ---- permuted scaled W_hh as f16 hi + scaled f16 residual ----
    for (int idx = tid; idx < 128 * 32; idx += 512) {
        int rp = idx >> 5, k = idx & 31;
        int orig; float scale; decode_row(rp, orig, scale);
        float wv = scale * W_hh[orig * H + k];
        _Float16 hi = (_Float16)wv;
        whi[idx] = hi;
        wlo[idx] = (_Float16)((wv - (float)hi) * RSC);
    }
    for (int idx = tid; idx < 2 * 16 * 32; idx += 512) {
        hhi_buf[idx] = (_Float16)0.f;
        hlo_buf[idx] = (_Float16)0.f;
    }
    __syncthreads();

    // A fragments: chunk-row = col, k = 8q + j (any per-lane k-layout is valid
    // as long as A and B packing agree — they do)
    const f16x8 Ahi = *reinterpret_cast<const f16x8*>(&whi[(16 * w + col) * 32 + 8 * q]);
    const f16x8 Alo = *reinterpret_cast<const f16x8*>(&wlo[(16 * w + col) * 32 + 8 * q]);

    const long xb = (long)(blockIdx.x * 16 + col) * SEQ;
    int vb = x[xb];          // token for s=0
    int vc = x[xb + 1];      // token for s=1
    f32x4 xg_cur = *reinterpret_cast<const f32x4*>(&xg_perm[vb * XRS + 16 * w + 4 * q]);

    float c = 0.0f, h = 0.0f;

    for (int s = 0; s < SEQ; ++s) {
        int vn = x[xb + ((s + 2) & (SEQ - 1))];                              // prefetch s+2
        f32x4 xg_nxt = *reinterpret_cast<const f32x4*>(
            &xg_perm[vc * XRS + 16 * w + 4 * q]);                            // prefetch s+1
        const int roff = ((s & 1) * 16 + col) * 32 + 8 * q;
        f16x8 Bhi = *reinterpret_cast<const f16x8*>(&hhi_buf[roff]);
        f16x8 Blo = *reinterpret_cast<const f16x8*>(&hlo_buf[roff]);

        f32x4 D  = __builtin_amdgcn_mfma_f32_16x16x32_f16(Ahi, Bhi, xg_cur, 0, 0, 0);
        f32x4 Dr = __builtin_amdgcn_mfma_f32_16x16x32_f16(Alo, Bhi,
                       f32x4{0.f, 0.f, 0.f, 0.f}, 0, 0, 0);
        Dr = __builtin_amdgcn_mfma_f32_16x16x32_f16(Ahi, Blo, Dr, 0, 0, 0);
        // D[r] + Dr[r]/2048 = -l2e*i, -l2e*f, -2l2e*g, -l2e*o of unit 4w+q, col
        float zi = __builtin_fmaf(RSCI, Dr[0], D[0]);
        float zf = __builtin_fmaf(RSCI, Dr[1], D[1]);
        float zg = __builtin_fmaf(RSCI, Dr[2], D[2]);
        float zo = __builtin_fmaf(RSCI, Dr[3], D[3]);

        float si = sig_exp2(zi);                         // sigma(i)
        float sf = sig_exp2(zf);                         // sigma(f)
        float ug = sig_exp2(zg);                         // sigma(2g)
        float so = sig_exp2(zo);                         // sigma(o)
        float gt = __builtin_fmaf(2.0f, ug, -1.0f);      // tanh(g)
        c = __builtin_fmaf(sf, c, si * gt);
        float tc = __builtin_fmaf(2.0f, sig_exp2(-2.0f * LOG2E * c), -1.0f); // tanh(c)
        h = so * tc;

        const int woff = (((s + 1) & 1) * 16 + col) * 32 + 4 * w + q;
        _Float16 hh = (_Float16)h;
        hhi_buf[woff] = hh;
        hlo_buf[woff] = (_Float16)((h - (float)hh) * RSC);
        __syncthreads();
        xg_cur = xg_nxt;
        vc = vn;
    }

    // ---- final FC (1 unit) + sigmoid: cross-wave reduce over the 32 units ----
    red[col * 32 + 4 * w + q] = h * W_fc[4 * w + q];
    __syncthreads();
    if (w == 0) {
        const f32x4* r4 = reinterpret_cast<const f32x4*>(&red[col * 32 + 8 * q]);
        f32x4 a = r4[0], b = r4[1];
        float p = a[0] + a[1] + a[2] + a[3] + b[0] + b[1] + b[2] + b[3];
        p += __shfl_xor(p, 16);
        p += __shfl_xor(p, 32);
        if (lane < 16) {
            out[blockIdx.x * 16 + col] = sig_exp2(-LOG2E * (p + b_fc[0]));
        }
    }
}

extern "C" void kernel_launch(void* const* d_in, const int* in_sizes, int n_in,
                              void* d_out, int out_size, void* d_ws, size_t ws_size,
                              hipStream_t stream) {
    const int*   x    = (const int*)d_in[0];
    const float* emb  = (const float*)d_in[1];
    const float* W_ih = (const float*)d_in[2];
    const float* W_hh = (const float*)d_in[3];
    const float* b_ih = (const float*)d_in[4];
    const float* b_hh = (const float*)d_in[5];
    const float* W_fc = (const float*)d_in[6];
    const float* b_fc = (const float*)d_in[7];
    float* out = (float*)d_out;

    dim3 grid(BATCH / 16);   // 256 blocks: one 16-elem group per block
    dim3 block(512);         // 8 waves, one mfma row-chunk each
    lstm_seq_classifier<<<grid, block, 0, stream>>>(x, emb, W_ih, W_hh,
                                                    b_ih, b_hh, W_fc, b_fc, out);
}

// Round 9
// 159.387 us; speedup vs baseline: 2.4435x; 1.1346x over previous
//
#include <hip/hip_runtime.h>

#define VOCAB 53
#define EDIM  16
#define H     32
#define SEQ   512
#define BATCH 4096
#define LOG2E 1.4426950408889634f
#define XRS   132   // xg row stride in f32 words (%4==0 for b128 alignment)
#define HS    72    // h-buffer per-col stride in f16: word-bank 4*(col+q) -> 2-way (free)
#define RSC   2048.0f      // residual scale (2^11) keeps lo parts in f16 normal range
#define RSCI  (1.0f/2048.0f)

typedef _Float16 f16x8 __attribute__((ext_vector_type(8)));
typedef float f32x4 __attribute__((ext_vector_type(4)));

__device__ __forceinline__ float exp2_hw(float x) {
    float r; asm("v_exp_f32 %0, %1" : "=v"(r) : "v"(x)); return r;
}
// rcp(1 + 2^xs): sigmoid when xs = -log2e * z (scales pre-folded into weights/tables)
__device__ __forceinline__ float sig_exp2(float xs) {
    return __builtin_amdgcn_rcpf(1.0f + exp2_hw(xs));
}

// permuted row rp = 16*m + 4*s + g  <->  original W row g*32 + (4m+s)
// (so mfma chunk m gives lane (q,c) the 4 gates i,f,g,o of unit 4m+q in D[0..3])
__device__ __forceinline__ void decode_row(int rp, int& orig, float& scale) {
    int m = rp >> 4, rem = rp & 15, s = rem >> 2, g = rem & 3;
    orig = g * 32 + 4 * m + s;
    scale = (g == 2) ? (-2.0f * LOG2E) : (-LOG2E);   // g-gate doubled: tanh(g)=2*sig(2g)-1
}

// 256 blocks x 512 threads. Each block owns 16 batch elements; its 8 waves
// split the 128 gate-rows (one 16x16x32 f16 MFMA row-chunk each; W rows
// permuted so each lane gets i,f,g,o of one hidden unit). h exchanged via a
// double-buffered PADDED LDS tile (stride 72 f16 -> 2-way banks, free), one
// barrier per step. Weights AND h carried as f16 hi + scaled-f16 residual
// (no subnormals); 3 MFMAs reconstruct near-f32 precision.
__global__ __launch_bounds__(512, 1)
void lstm_seq_classifier(const int* __restrict__ x,
                         const float* __restrict__ emb,
                         const float* __restrict__ W_ih,
                         const float* __restrict__ W_hh,
                         const float* __restrict__ b_ih,
                         const float* __restrict__ b_hh,
                         const float* __restrict__ W_fc,
                         const float* __restrict__ b_fc,
                         float* __restrict__ out) {
    __shared__ float xg_perm[VOCAB * XRS];                  // 27,984 B (f32, exact)
    __shared__ _Float16 whi[128 * 32];                      // 8,192 B
    __shared__ _Float16 wlo[128 * 32];                      // 8,192 B (x2048 residual)
    __shared__ __align__(16) _Float16 hhi_buf[2][16][HS];   // 4,608 B
    __shared__ __align__(16) _Float16 hlo_buf[2][16][HS];   // 4,608 B (x2048 residual)
    __shared__ float red[16 * 33];                          // 2,112 B

    const int tid  = threadIdx.x;
    const int lane = tid & 63;
    const int w    = tid >> 6;      // wave index = mfma row-chunk m
    const int col  = lane & 15;     // batch column (B/C/D col) & A row-in-chunk
    const int q    = lane >> 4;

    // ---- vocab -> permuted, scaled gate-preactivation table (f32 exact) ----
    for (int idx = tid; idx < VOCAB * 128; idx += 512) {
        int v = idx >> 7, rp = idx & 127;
        int orig; float scale; decode_row(rp, orig, scale);
        float acc = b_ih[orig] + b_hh[orig];
        const float* ev = emb + v * EDIM;
        const float* wr = W_ih + orig * EDIM;
#pragma unroll
        for (int e = 0; e < EDIM; ++e) acc += ev[e] * wr[e];
        xg_perm[v * XRS + rp] = scale * acc;
    }
    // ---- permuted scaled W_hh as f16 hi + scaled f16 residual ----
    for (int idx = tid; idx < 128 * 32; idx += 512) {
        int rp = idx >> 5, k = idx & 31;
        int orig; float scale; decode_row(rp, orig, scale);
        float wv = scale * W_hh[orig * H + k];
        _Float16 hi = (_Float16)wv;
        whi[idx] = hi;
        wlo[idx] = (_Float16)((wv - (float)hi) * RSC);
    }
    for (int idx = tid; idx < 2 * 16 * HS; idx += 512) {
        (&hhi_buf[0][0][0])[idx] = (_Float16)0.f;
        (&hlo_buf[0][0][0])[idx] = (_Float16)0.f;
    }
    __syncthreads();

    // A fragments: chunk-row = col, k = 8q + j (A and B packed with the same rule)
    const f16x8 Ahi = *reinterpret_cast<const f16x8*>(&whi[(16 * w + col) * 32 + 8 * q]);
    const f16x8 Alo = *reinterpret_cast<const f16x8*>(&wlo[(16 * w + col) * 32 + 8 * q]);

    const long xb = (long)(blockIdx.x * 16 + col) * SEQ;
    int vb = x[xb];          // token for s=0
    int vc = x[xb + 1];      // token for s=1
    f32x4 xg_cur = *reinterpret_cast<const f32x4*>(&xg_perm[vb * XRS + 16 * w + 4 * q]);

    float c = 0.0f, h = 0.0f;

    for (int s = 0; s < SEQ; ++s) {
        int vn = x[xb + ((s + 2) & (SEQ - 1))];                              // prefetch s+2
        f32x4 xg_nxt = *reinterpret_cast<const f32x4*>(
            &xg_perm[vc * XRS + 16 * w + 4 * q]);                            // prefetch s+1
        const int rb = s & 1;
        f16x8 Bhi = *reinterpret_cast<const f16x8*>(&hhi_buf[rb][col][8 * q]);
        f16x8 Blo = *reinterpret_cast<const f16x8*>(&hlo_buf[rb][col][8 * q]);

        f32x4 D  = __builtin_amdgcn_mfma_f32_16x16x32_f16(Ahi, Bhi, xg_cur, 0, 0, 0);
        f32x4 Dr = __builtin_amdgcn_mfma_f32_16x16x32_f16(Alo, Bhi,
                       f32x4{0.f, 0.f, 0.f, 0.f}, 0, 0, 0);
        Dr = __builtin_amdgcn_mfma_f32_16x16x32_f16(Ahi, Blo, Dr, 0, 0, 0);
        // D[r] + Dr[r]/2048 = -l2e*i, -l2e*f, -2l2e*g, -l2e*o of unit 4w+q, col
        float zi = __builtin_fmaf(RSCI, Dr[0], D[0]);
        float zf = __builtin_fmaf(RSCI, Dr[1], D[1]);
        float zg = __builtin_fmaf(RSCI, Dr[2], D[2]);
        float zo = __builtin_fmaf(RSCI, Dr[3], D[3]);

        float si = sig_exp2(zi);                         // sigma(i)
        float sf = sig_exp2(zf);                         // sigma(f)
        float ug = sig_exp2(zg);                         // sigma(2g)
        float so = sig_exp2(zo);                         // sigma(o)
        float gt = __builtin_fmaf(2.0f, ug, -1.0f);      // tanh(g)
        c = __builtin_fmaf(sf, c, si * gt);
        float tc = __builtin_fmaf(2.0f, sig_exp2(-2.0f * LOG2E * c), -1.0f); // tanh(c)
        h = so * tc;

        const int nb = (s + 1) & 1;
        _Float16 hh = (_Float16)h;
        hhi_buf[nb][col][4 * w + q] = hh;
        hlo_buf[nb][col][4 * w + q] = (_Float16)((h - (float)hh) * RSC);
        __syncthreads();
        xg_cur = xg_nxt;
        vc = vn;
    }

    // ---- final FC (1 unit) + sigmoid: cross-wave reduce over the 32 units ----
    red[col * 33 + 4 * w + q] = h * W_fc[4 * w + q];
    __syncthreads();
    if (w == 0) {
        const float* rr = &red[col * 33];
        float p = 0.f;
#pragma unroll
        for (int u = 0; u < 8; ++u) p += rr[8 * q + u] ;
        p += __shfl_xor(p, 16);
        p += __shfl_xor(p, 32);
        if (lane < 16) {
            out[blockIdx.x * 16 + col] = sig_exp2(-LOG2E * (p + b_fc[0]));
        }
    }
}

extern "C" void kernel_launch(void* const* d_in, const int* in_sizes, int n_in,
                              void* d_out, int out_size, void* d_ws, size_t ws_size,
                              hipStream_t stream) {
    const int*   x    = (const int*)d_in[0];
    const float* emb  = (const float*)d_in[1];
    const float* W_ih = (const float*)d_in[2];
    const float* W_hh = (const float*)d_in[3];
    const float* b_ih = (const float*)d_in[4];
    const float* b_hh = (const float*)d_in[5];
    const float* W_fc = (const float*)d_in[6];
    const float* b_fc = (const float*)d_in[7];
    float* out = (float*)d_out;

    dim3 grid(BATCH / 16);   // 256 blocks: one 16-elem group per block
    dim3 block(512);         // 8 waves, one mfma row-chunk each
    lstm_seq_classifier<<<grid, block, 0, stream>>>(x, emb, W_ih, W_hh,
                                                    b_ih, b_hh, W_fc, b_fc, out);
}